// Round 7
// baseline (263.468 us; speedup 1.0000x reference)
//
#include <hip/hip_runtime.h>
#include <hip/hip_bf16.h>

#define D 128
#define NH 256
#define K1 384
#define BM 64
#define NTILES 5000
#define NBLK 256
#define NNODES 10000

typedef __attribute__((ext_vector_type(8))) short bf16x8;
typedef __attribute__((ext_vector_type(4))) float f32x4;

__device__ __forceinline__ unsigned short f2b(float f) {
  unsigned int u = __builtin_bit_cast(unsigned int, f);
  u += 0x7fffu + ((u >> 16) & 1u);   // round-to-nearest-even
  return (unsigned short)(u >> 16);
}

// nodes fp32 -> bf16 table
__global__ void cast_nodes_kernel(const float* __restrict__ nodes,
                                  ushort* __restrict__ out) {
  int i = (blockIdx.x * 256 + threadIdx.x) * 4;
  float4 v = *(const float4*)(nodes + i);
  ushort4 b;
  b.x = f2b(v.x); b.y = f2b(v.y); b.z = f2b(v.z); b.w = f2b(v.w);
  *(ushort4*)(out + i) = b;
}

// Pack W1 (fp32 [512][256], rows 0..383 used) into MFMA-fragment order:
// chunk c = nt*12 + ks ; lane l holds W1[ks*32+(l>>4)*8 + j][nt*16+(l&15)]
__global__ void pack_w1_kernel(const float* __restrict__ W1,
                               ushort* __restrict__ W1p) {
  int c = blockIdx.x * 256 + threadIdx.x;   // 12288 threads
  int nt = c / (12 * 64);
  int rem = c % (12 * 64);
  int ks = rem >> 6;
  int l = rem & 63;
  int col = nt * 16 + (l & 15);
  int k0 = ks * 32 + (l >> 4) * 8;
  ushort* dst = W1p + (size_t)c * 8;
  #pragma unroll
  for (int j = 0; j < 8; ++j)
    dst[j] = f2b(W1[(size_t)(k0 + j) * NH + col]);
}

// Pack W2 (fp32 [256][128]) same fragment order: chunk c = nt2*8 + ks
__global__ void pack_w2_kernel(const float* __restrict__ W2,
                               ushort* __restrict__ W2p) {
  int c = blockIdx.x * 256 + threadIdx.x;   // 4096 threads
  int nt2 = c / (8 * 64);
  int rem = c % (8 * 64);
  int ks = rem >> 6;
  int l = rem & 63;
  int col = nt2 * 16 + (l & 15);
  int k0 = ks * 32 + (l >> 4) * 8;
  ushort* dst = W2p + (size_t)c * 8;
  #pragma unroll
  for (int j = 0; j < 8; ++j)
    dst[j] = f2b(W2[(size_t)(k0 + j) * D + col]);
}

// cvec[n] = b1[n] + sum_k globals[k] * W1[384+k][n]
__global__ void cvec_kernel(const float* __restrict__ W1,
                            const float* __restrict__ b1,
                            const float* __restrict__ g,
                            float* __restrict__ cvec) {
  int n = threadIdx.x;  // 256
  float acc = b1[n];
  for (int k = 0; k < D; ++k)
    acc += g[k] * W1[(size_t)(K1 + k) * NH + n];
  cvec[n] = acc;
}

// Persistent: 256 blocks (1/CU), each loops over ~20 tiles of 64 edges.
// X double-buffered in LDS; W1/W2 streamed from L2 as packed fragments
// (double-buffered in 16 VGPRs — NO large register arrays, spill-free).
__global__ __launch_bounds__(512, 2) void fused_kernel(
    const float* __restrict__ edges,
    const ushort* __restrict__ nodes_b,
    const int* __restrict__ receivers,
    const int* __restrict__ senders,
    const ushort* __restrict__ W1p,    // packed fragments, 16nt x 12ks x 64lane x 8
    const float* __restrict__ cvec,    // [256]
    const ushort* __restrict__ W2p,    // packed fragments, 8nt x 8ks x 64lane x 8
    const float* __restrict__ b2,      // [128]
    float* __restrict__ out) {
  __shared__ char Xs[2][BM * 768];    // 2 x 48 KB, byte ^= (row&7)<<4 swizzle
  __shared__ char Hs[BM * 512];       // 32 KB, same swizzle

  const int tid = threadIdx.x;
  const int lane = tid & 63;
  const int wave = tid >> 6;
  const int lr = lane & 15;
  const int kg = lane >> 4;
  const int gr0 = tid >> 4;           // 0..31
  const int gr1 = gr0 + 32;           // 32..63
  const int gc = (tid & 15) << 3;     // bf16 col chunk

  // loop-invariant constants
  float cv[2];
  #pragma unroll
  for (int n = 0; n < 2; ++n) cv[n] = cvec[wave * 32 + n * 16 + lr];
  const int wm2 = wave >> 2;          // GEMM2: 2x4 wave grid
  const int wn2 = wave & 3;
  float bias2[2];
  #pragma unroll
  for (int n = 0; n < 2; ++n) bias2[n] = b2[wn2 * 32 + n * 16 + lr];
  const ushort* w1base = W1p + (size_t)(wave * 2) * 12 * 512 + lane * 8;
  const ushort* w2base = W2p + (size_t)(wn2 * 2) * 8 * 512 + lane * 8;

  // ---- prologue: stage first tile into Xs[0]
  int t = blockIdx.x;
  {
    const int eb = t * BM;
    int ir0 = receivers[eb + gr0], ir1 = receivers[eb + gr1];
    int is0 = senders[eb + gr0],  is1 = senders[eb + gr1];
    float4 ev[4]; int er[4], ec[4];
    #pragma unroll
    for (int it = 0; it < 4; ++it) {
      int ch = tid + it * 512;
      er[it] = ch >> 5; ec[it] = (ch & 31) << 2;
      ev[it] = *(const float4*)(edges + (size_t)(eb + er[it]) * D + ec[it]);
    }
    uint4 g0 = *(const uint4*)(nodes_b + (size_t)ir0 * D + gc);
    uint4 g1 = *(const uint4*)(nodes_b + (size_t)ir1 * D + gc);
    uint4 g2 = *(const uint4*)(nodes_b + (size_t)is0 * D + gc);
    uint4 g3 = *(const uint4*)(nodes_b + (size_t)is1 * D + gc);
    #pragma unroll
    for (int it = 0; it < 4; ++it) {
      ushort4 b;
      b.x = f2b(ev[it].x); b.y = f2b(ev[it].y); b.z = f2b(ev[it].z); b.w = f2b(ev[it].w);
      *(ushort4*)(Xs[0] + er[it] * 768 + ((ec[it] * 2) ^ ((er[it] & 7) << 4))) = b;
    }
    int cR = (D + gc) * 2, cS = (2 * D + gc) * 2;
    *(uint4*)(Xs[0] + gr0 * 768 + (cR ^ ((gr0 & 7) << 4))) = g0;
    *(uint4*)(Xs[0] + gr1 * 768 + (cR ^ ((gr1 & 7) << 4))) = g1;
    *(uint4*)(Xs[0] + gr0 * 768 + (cS ^ ((gr0 & 7) << 4))) = g2;
    *(uint4*)(Xs[0] + gr1 * 768 + (cS ^ ((gr1 & 7) << 4))) = g3;
  }
  __syncthreads();

  int cur = 0;
  for (; t < NTILES; t += NBLK) {
    const int tn = t + NBLK;
    const bool hn = (tn < NTILES);
    const int ebn = (hn ? tn : t) * BM;   // clamped: loads safe, writes skipped
    const int eb = t * BM;

    // ---- next-tile index + edge loads issued EARLY (hide under GEMM1)
    int ir0 = receivers[ebn + gr0], ir1 = receivers[ebn + gr1];
    int is0 = senders[ebn + gr0],  is1 = senders[ebn + gr1];
    float4 ev[4]; int er[4], ec[4];
    #pragma unroll
    for (int it = 0; it < 4; ++it) {
      int ch = tid + it * 512;
      er[it] = ch >> 5; ec[it] = (ch & 31) << 2;
      ev[it] = *(const float4*)(edges + (size_t)(ebn + er[it]) * D + ec[it]);
    }

    // ---- GEMM1: [64x384] @ [384x32-per-wave], A from LDS, B streamed (dbuf)
    f32x4 acc[4][2] = {};
    const char* xb = Xs[cur];
    bf16x8 bb[2][2];
    #pragma unroll
    for (int n = 0; n < 2; ++n)
      bb[0][n] = *(const bf16x8*)(w1base + (size_t)n * 12 * 512);
    #pragma unroll
    for (int ks = 0; ks < 12; ++ks) {
      const int c1 = ks & 1, nx = c1 ^ 1;
      if (ks < 11) {
        #pragma unroll
        for (int n = 0; n < 2; ++n)
          bb[nx][n] = *(const bf16x8*)(w1base + (size_t)n * 12 * 512 + (ks + 1) * 512);
      }
      const int k0 = ks * 32 + kg * 8;
      bf16x8 a[4];
      #pragma unroll
      for (int m = 0; m < 4; ++m) {
        int row = m * 16 + lr;
        a[m] = *(const bf16x8*)(xb + row * 768 + ((k0 * 2) ^ ((row & 7) << 4)));
      }
      __builtin_amdgcn_s_setprio(1);
      #pragma unroll
      for (int m = 0; m < 4; ++m)
        #pragma unroll
        for (int n = 0; n < 2; ++n)
          acc[m][n] = __builtin_amdgcn_mfma_f32_16x16x32_bf16(a[m], bb[c1][n], acc[m][n], 0, 0, 0);
      __builtin_amdgcn_s_setprio(0);
    }

    // ---- next-tile gathers (idx long resolved by now)
    uint4 g0 = *(const uint4*)(nodes_b + (size_t)ir0 * D + gc);
    uint4 g1 = *(const uint4*)(nodes_b + (size_t)ir1 * D + gc);
    uint4 g2 = *(const uint4*)(nodes_b + (size_t)is0 * D + gc);
    uint4 g3 = *(const uint4*)(nodes_b + (size_t)is1 * D + gc);

    // ---- epilogue 1: + cvec, relu, -> bf16 Hs
    #pragma unroll
    for (int n = 0; n < 2; ++n) {
      int col = wave * 32 + n * 16 + lr;
      #pragma unroll
      for (int m = 0; m < 4; ++m) {
        #pragma unroll
        for (int r = 0; r < 4; ++r) {
          int row = m * 16 + kg * 4 + r;
          float v = acc[m][n][r] + cv[n];
          v = v > 0.f ? v : 0.f;
          *(ushort*)(Hs + row * 512 + ((col * 2) ^ ((row & 7) << 4))) = f2b(v);
        }
      }
    }

    // prefetch first W2 fragments (no Hs dependency) before the barrier
    bf16x8 b2b[2][2];
    #pragma unroll
    for (int n = 0; n < 2; ++n)
      b2b[0][n] = *(const bf16x8*)(w2base + (size_t)n * 8 * 512);
    __syncthreads();

    // ---- GEMM2: [64x256] @ [256x128], 2x4 wave grid, W2 streamed (dbuf)
    f32x4 acc2[2][2] = {};
    #pragma unroll
    for (int ks = 0; ks < 8; ++ks) {
      const int c2 = ks & 1, nx = c2 ^ 1;
      if (ks < 7) {
        #pragma unroll
        for (int n = 0; n < 2; ++n)
          b2b[nx][n] = *(const bf16x8*)(w2base + (size_t)n * 8 * 512 + (ks + 1) * 512);
      }
      const int k0 = ks * 32 + kg * 8;
      bf16x8 a[2];
      #pragma unroll
      for (int m = 0; m < 2; ++m) {
        int row = wm2 * 32 + m * 16 + lr;
        a[m] = *(const bf16x8*)(Hs + row * 512 + ((k0 * 2) ^ ((row & 7) << 4)));
      }
      __builtin_amdgcn_s_setprio(1);
      #pragma unroll
      for (int m = 0; m < 2; ++m)
        #pragma unroll
        for (int n = 0; n < 2; ++n)
          acc2[m][n] = __builtin_amdgcn_mfma_f32_16x16x32_bf16(a[m], b2b[c2][n], acc2[m][n], 0, 0, 0);
      __builtin_amdgcn_s_setprio(0);
    }

    // ---- stage next tile into the other X buffer (regs -> LDS)
    if (hn) {
      char* xn = Xs[cur ^ 1];
      #pragma unroll
      for (int it = 0; it < 4; ++it) {
        ushort4 b;
        b.x = f2b(ev[it].x); b.y = f2b(ev[it].y); b.z = f2b(ev[it].z); b.w = f2b(ev[it].w);
        *(ushort4*)(xn + er[it] * 768 + ((ec[it] * 2) ^ ((er[it] & 7) << 4))) = b;
      }
      int cR = (D + gc) * 2, cS = (2 * D + gc) * 2;
      *(uint4*)(xn + gr0 * 768 + (cR ^ ((gr0 & 7) << 4))) = g0;
      *(uint4*)(xn + gr1 * 768 + (cR ^ ((gr1 & 7) << 4))) = g1;
      *(uint4*)(xn + gr0 * 768 + (cS ^ ((gr0 & 7) << 4))) = g2;
      *(uint4*)(xn + gr1 * 768 + (cS ^ ((gr1 & 7) << 4))) = g3;
    }

    // ---- epilogue 2: + b2, store fp32 (wave's 32x32 tile)
    #pragma unroll
    for (int n = 0; n < 2; ++n) {
      int col = wn2 * 32 + n * 16 + lr;
      #pragma unroll
      for (int m = 0; m < 2; ++m) {
        #pragma unroll
        for (int r = 0; r < 4; ++r) {
          int row = wm2 * 32 + m * 16 + kg * 4 + r;
          out[(size_t)(eb + row) * D + col] = acc2[m][n][r] + bias2[n];
        }
      }
    }
    __syncthreads();
    cur ^= 1;
  }
}

extern "C" void kernel_launch(void* const* d_in, const int* in_sizes, int n_in,
                              void* d_out, int out_size, void* d_ws, size_t ws_size,
                              hipStream_t stream) {
  const float* edges     = (const float*)d_in[0];
  const float* nodes     = (const float*)d_in[1];
  const float* globals_  = (const float*)d_in[2];
  const int*   receivers = (const int*)d_in[3];
  const int*   senders   = (const int*)d_in[4];
  const float* W1        = (const float*)d_in[5];
  const float* b1        = (const float*)d_in[6];
  const float* W2        = (const float*)d_in[7];
  const float* b2        = (const float*)d_in[8];
  float* out = (float*)d_out;

  char* ws = (char*)d_ws;
  ushort* nodes_b = (ushort*)ws;                                // 2,560,000 B
  ushort* W1p     = (ushort*)(ws + 2560000);                    //   196,608 B
  ushort* W2p     = (ushort*)(ws + 2560000 + 196608);           //    65,536 B
  float*  cvec    = (float*)(ws + 2560000 + 196608 + 65536);    //     1,024 B

  hipLaunchKernelGGL(cast_nodes_kernel, dim3(NNODES * D / 1024), dim3(256), 0, stream,
                     nodes, nodes_b);
  hipLaunchKernelGGL(pack_w1_kernel, dim3(48), dim3(256), 0, stream, W1, W1p);
  hipLaunchKernelGGL(pack_w2_kernel, dim3(16), dim3(256), 0, stream, W2, W2p);
  hipLaunchKernelGGL(cvec_kernel, dim3(1), dim3(256), 0, stream,
                     W1, b1, globals_, cvec);
  hipLaunchKernelGGL(fused_kernel, dim3(NBLK), dim3(512), 0, stream,
                     edges, nodes_b, receivers, senders, W1p, cvec, W2p, b2, out);
}

// Round 8
// 156.592 us; speedup vs baseline: 1.6825x; 1.6825x over previous
//
#include <hip/hip_runtime.h>
#include <hip/hip_bf16.h>

#define D 128
#define NH 256
#define K1 384
#define BM 64
#define E_TOTAL 320000
#define NNODES 10000

typedef __attribute__((ext_vector_type(8))) short bf16x8;
typedef __attribute__((ext_vector_type(4))) float f32x4;

__device__ __forceinline__ unsigned short f2b(float f) {
  unsigned int u = __builtin_bit_cast(unsigned int, f);
  u += 0x7fffu + ((u >> 16) & 1u);   // round-to-nearest-even
  return (unsigned short)(u >> 16);
}

// nodes fp32 -> bf16 table
__global__ void cast_nodes_kernel(const float* __restrict__ nodes,
                                  ushort* __restrict__ out) {
  int i = (blockIdx.x * 256 + threadIdx.x) * 4;
  float4 v = *(const float4*)(nodes + i);
  ushort4 b;
  b.x = f2b(v.x); b.y = f2b(v.y); b.z = f2b(v.z); b.w = f2b(v.w);
  *(ushort4*)(out + i) = b;
}

// Pack W1 (fp32 [512][256], rows 0..383 used) into MFMA-fragment order:
// chunk c = nt*12 + ks ; lane l holds W1[ks*32+(l>>4)*8 + j][nt*16+(l&15)]
// (same layout serves as A-operand = W1^T fragments: lane&15 = hidden idx)
__global__ void pack_w1_kernel(const float* __restrict__ W1,
                               ushort* __restrict__ W1p) {
  int c = blockIdx.x * 256 + threadIdx.x;   // 12288 threads
  int nt = c / (12 * 64);
  int rem = c % (12 * 64);
  int ks = rem >> 6;
  int l = rem & 63;
  int col = nt * 16 + (l & 15);
  int k0 = ks * 32 + (l >> 4) * 8;
  ushort* dst = W1p + (size_t)c * 8;
  #pragma unroll
  for (int j = 0; j < 8; ++j)
    dst[j] = f2b(W1[(size_t)(k0 + j) * NH + col]);
}

// Pack W2 (fp32 [256][128]) same fragment order: chunk c = nt2*8 + ks
__global__ void pack_w2_kernel(const float* __restrict__ W2,
                               ushort* __restrict__ W2p) {
  int c = blockIdx.x * 256 + threadIdx.x;   // 4096 threads
  int nt2 = c / (8 * 64);
  int rem = c % (8 * 64);
  int ks = rem >> 6;
  int l = rem & 63;
  int col = nt2 * 16 + (l & 15);
  int k0 = ks * 32 + (l >> 4) * 8;
  ushort* dst = W2p + (size_t)c * 8;
  #pragma unroll
  for (int j = 0; j < 8; ++j)
    dst[j] = f2b(W2[(size_t)(k0 + j) * D + col]);
}

// cvec[n] = b1[n] + sum_k globals[k] * W1[384+k][n]
__global__ void cvec_kernel(const float* __restrict__ W1,
                            const float* __restrict__ b1,
                            const float* __restrict__ g,
                            float* __restrict__ cvec) {
  int n = threadIdx.x;  // 256
  float acc = b1[n];
  for (int k = 0; k < D; ++k)
    acc += g[k] * W1[(size_t)(K1 + k) * NH + n];
  cvec[n] = acc;
}

// Swapped (transposed) fused kernel: computes H^T = W1^T X^T and out^T = W2^T H^T.
// A/B fragment layouts are symmetric, so the same packed W fragments serve as
// A-operands and the same LDS X-row reads serve as B-operands. Each lane's acc
// quad = 4 consecutive hidden/out columns of ONE edge -> vector epilogues.
__global__ __launch_bounds__(512, 4) void fused_kernel(
    const float* __restrict__ edges,
    const ushort* __restrict__ nodes_b,
    const int* __restrict__ receivers,
    const int* __restrict__ senders,
    const ushort* __restrict__ W1p,    // packed fragments, 16nt x 12ks x 64lane x 8
    const float* __restrict__ cvec,    // [256]
    const ushort* __restrict__ W2p,    // packed fragments, 8nt x 8ks x 64lane x 8
    const float* __restrict__ b2,      // [128]
    float* __restrict__ out) {
  __shared__ char Xs[BM * 768];   // 64 x 384 bf16, byte ^= (row&7)<<4 swizzle
  __shared__ char Hs[BM * 512];   // 64 rows(edges) x 256 cols(hidden) bf16, same swizzle

  const int ebase = blockIdx.x * BM;
  const int tid = threadIdx.x;

  // ---- gather indices first
  const int gr0 = tid >> 4;
  const int gr1 = gr0 + 32;
  const int gc = (tid & 15) << 3;
  int idx_r0 = receivers[ebase + gr0];
  int idx_r1 = receivers[ebase + gr1];
  int idx_s0 = senders[ebase + gr0];
  int idx_s1 = senders[ebase + gr1];

  // ---- edge loads
  float4 ev[4];
  int er[4], ec[4];
  #pragma unroll
  for (int it = 0; it < 4; ++it) {
    int ch = tid + it * 512;
    er[it] = ch >> 5;
    ec[it] = (ch & 31) << 2;
    ev[it] = *(const float4*)(edges + (size_t)(ebase + er[it]) * D + ec[it]);
  }

  // ---- gathers
  uint4 gv[4];
  gv[0] = *(const uint4*)(nodes_b + (size_t)idx_r0 * D + gc);
  gv[1] = *(const uint4*)(nodes_b + (size_t)idx_r1 * D + gc);
  gv[2] = *(const uint4*)(nodes_b + (size_t)idx_s0 * D + gc);
  gv[3] = *(const uint4*)(nodes_b + (size_t)idx_s1 * D + gc);

  // ---- convert + LDS writes
  #pragma unroll
  for (int it = 0; it < 4; ++it) {
    ushort4 b;
    b.x = f2b(ev[it].x); b.y = f2b(ev[it].y); b.z = f2b(ev[it].z); b.w = f2b(ev[it].w);
    *(ushort4*)(Xs + er[it] * 768 + ((ec[it] * 2) ^ ((er[it] & 7) << 4))) = b;
  }
  {
    int cR = (D + gc) * 2, cS = (2 * D + gc) * 2;
    *(uint4*)(Xs + gr0 * 768 + (cR ^ ((gr0 & 7) << 4))) = gv[0];
    *(uint4*)(Xs + gr1 * 768 + (cR ^ ((gr1 & 7) << 4))) = gv[1];
    *(uint4*)(Xs + gr0 * 768 + (cS ^ ((gr0 & 7) << 4))) = gv[2];
    *(uint4*)(Xs + gr1 * 768 + (cS ^ ((gr1 & 7) << 4))) = gv[3];
  }
  __syncthreads();

  const int lane = tid & 63;
  const int wave = tid >> 6;     // GEMM1: wave owns hidden cols [32w, 32w+32)
  const int lr = lane & 15;
  const int kg = lane >> 4;

  // epilogue-1 constants: cvec[h], h = wave*32 + ht*16 + kg*4 + r
  float cv_[2][4];
  #pragma unroll
  for (int ht = 0; ht < 2; ++ht)
    #pragma unroll
    for (int r = 0; r < 4; ++r)
      cv_[ht][r] = cvec[wave * 32 + ht * 16 + kg * 4 + r];

  // GEMM2 wave grid: 4 out-col groups x 2 edge groups
  const int wm3 = wave >> 1;     // 0..3 : out cols [32*wm3, 32*wm3+32)
  const int wn3 = wave & 1;      // 0..1 : edges [32*wn3, 32*wn3+32)
  float bias_[2][4];
  #pragma unroll
  for (int mt = 0; mt < 2; ++mt)
    #pragma unroll
    for (int r = 0; r < 4; ++r)
      bias_[mt][r] = b2[wm3 * 32 + mt * 16 + kg * 4 + r];

  // ---- GEMM1 (swapped): H^T[32h x 64e] += W1^T-frag (A) * X-row-frag (B)
  const ushort* w1base = W1p + (size_t)(wave * 2) * 12 * 512 + lane * 8;

  f32x4 acc[2][4] = {};   // [ht][et]
  bf16x8 aw[2][2];
  #pragma unroll
  for (int ht = 0; ht < 2; ++ht)
    aw[0][ht] = *(const bf16x8*)(w1base + (size_t)ht * 12 * 512);

  #pragma unroll
  for (int ks = 0; ks < 12; ++ks) {
    const int cur = ks & 1, nxt = cur ^ 1;
    if (ks < 11) {
      #pragma unroll
      for (int ht = 0; ht < 2; ++ht)
        aw[nxt][ht] = *(const bf16x8*)(w1base + (size_t)ht * 12 * 512 + (ks + 1) * 512);
    }
    const int k0 = ks * 32 + kg * 8;
    bf16x8 xb[4];
    #pragma unroll
    for (int et = 0; et < 4; ++et) {
      int row = et * 16 + lr;
      xb[et] = *(const bf16x8*)(Xs + row * 768 + ((k0 * 2) ^ ((row & 7) << 4)));
    }
    #pragma unroll
    for (int ht = 0; ht < 2; ++ht)
      #pragma unroll
      for (int et = 0; et < 4; ++et)
        acc[ht][et] = __builtin_amdgcn_mfma_f32_16x16x32_bf16(aw[cur][ht], xb[et], acc[ht][et], 0, 0, 0);
  }

  // ---- epilogue 1: + cvec, relu -> bf16, vector ds_write_b64 (4 cols of one edge)
  #pragma unroll
  for (int ht = 0; ht < 2; ++ht) {
    const int h0b = (wave * 32 + ht * 16 + kg * 4) * 2;  // byte offset of h0 in row
    #pragma unroll
    for (int et = 0; et < 4; ++et) {
      int e = et * 16 + lr;
      float v0 = acc[ht][et][0] + cv_[ht][0];
      float v1 = acc[ht][et][1] + cv_[ht][1];
      float v2 = acc[ht][et][2] + cv_[ht][2];
      float v3 = acc[ht][et][3] + cv_[ht][3];
      v0 = v0 > 0.f ? v0 : 0.f;
      v1 = v1 > 0.f ? v1 : 0.f;
      v2 = v2 > 0.f ? v2 : 0.f;
      v3 = v3 > 0.f ? v3 : 0.f;
      uint2 pk;
      pk.x = (unsigned)f2b(v0) | ((unsigned)f2b(v1) << 16);
      pk.y = (unsigned)f2b(v2) | ((unsigned)f2b(v3) << 16);
      *(uint2*)(Hs + e * 512 + (h0b ^ ((e & 7) << 4))) = pk;
    }
  }

  // prefetch first W2^T fragments (no Hs dependency) before the barrier
  const ushort* w2base = W2p + (size_t)(wm3 * 2) * 8 * 512 + lane * 8;
  bf16x8 aw2[2][2];
  #pragma unroll
  for (int mt = 0; mt < 2; ++mt)
    aw2[0][mt] = *(const bf16x8*)(w2base + (size_t)mt * 8 * 512);
  __syncthreads();

  // ---- GEMM2 (swapped): out^T[32c x 32e] += W2^T-frag (A) * H-row-frag (B)
  f32x4 acc2[2][2] = {};  // [mt][et2]
  #pragma unroll
  for (int ks = 0; ks < 8; ++ks) {
    const int cur = ks & 1, nxt = cur ^ 1;
    if (ks < 7) {
      #pragma unroll
      for (int mt = 0; mt < 2; ++mt)
        aw2[nxt][mt] = *(const bf16x8*)(w2base + (size_t)mt * 8 * 512 + (ks + 1) * 512);
    }
    const int k0 = ks * 32 + kg * 8;
    bf16x8 hb[2];
    #pragma unroll
    for (int et2 = 0; et2 < 2; ++et2) {
      int e = wn3 * 32 + et2 * 16 + lr;
      hb[et2] = *(const bf16x8*)(Hs + e * 512 + ((k0 * 2) ^ ((e & 7) << 4)));
    }
    #pragma unroll
    for (int mt = 0; mt < 2; ++mt)
      #pragma unroll
      for (int et2 = 0; et2 < 2; ++et2)
        acc2[mt][et2] = __builtin_amdgcn_mfma_f32_16x16x32_bf16(aw2[cur][mt], hb[et2], acc2[mt][et2], 0, 0, 0);
  }

  // ---- epilogue 2: + b2, float4 stores (4 consecutive out cols of one edge;
  // a wave instruction covers 16 edges x full 64B sectors)
  #pragma unroll
  for (int mt = 0; mt < 2; ++mt) {
    const int c0 = wm3 * 32 + mt * 16 + kg * 4;
    #pragma unroll
    for (int et2 = 0; et2 < 2; ++et2) {
      int e = wn3 * 32 + et2 * 16 + lr;
      float4 o;
      o.x = acc2[mt][et2][0] + bias_[mt][0];
      o.y = acc2[mt][et2][1] + bias_[mt][1];
      o.z = acc2[mt][et2][2] + bias_[mt][2];
      o.w = acc2[mt][et2][3] + bias_[mt][3];
      *(float4*)(out + (size_t)(ebase + e) * D + c0) = o;
    }
  }
}

extern "C" void kernel_launch(void* const* d_in, const int* in_sizes, int n_in,
                              void* d_out, int out_size, void* d_ws, size_t ws_size,
                              hipStream_t stream) {
  const float* edges     = (const float*)d_in[0];
  const float* nodes     = (const float*)d_in[1];
  const float* globals_  = (const float*)d_in[2];
  const int*   receivers = (const int*)d_in[3];
  const int*   senders   = (const int*)d_in[4];
  const float* W1        = (const float*)d_in[5];
  const float* b1        = (const float*)d_in[6];
  const float* W2        = (const float*)d_in[7];
  const float* b2        = (const float*)d_in[8];
  float* out = (float*)d_out;

  char* ws = (char*)d_ws;
  ushort* nodes_b = (ushort*)ws;                                // 2,560,000 B
  ushort* W1p     = (ushort*)(ws + 2560000);                    //   196,608 B
  ushort* W2p     = (ushort*)(ws + 2560000 + 196608);           //    65,536 B
  float*  cvec    = (float*)(ws + 2560000 + 196608 + 65536);    //     1,024 B

  hipLaunchKernelGGL(cast_nodes_kernel, dim3(NNODES * D / 1024), dim3(256), 0, stream,
                     nodes, nodes_b);
  hipLaunchKernelGGL(pack_w1_kernel, dim3(48), dim3(256), 0, stream, W1, W1p);
  hipLaunchKernelGGL(pack_w2_kernel, dim3(16), dim3(256), 0, stream, W2, W2p);
  hipLaunchKernelGGL(cvec_kernel, dim3(1), dim3(256), 0, stream,
                     W1, b1, globals_, cvec);
  hipLaunchKernelGGL(fused_kernel, dim3(E_TOTAL / BM), dim3(512), 0, stream,
                     edges, nodes_b, receivers, senders, W1p, cvec, W2p, b2, out);
}

// Round 9
// 151.832 us; speedup vs baseline: 1.7353x; 1.0313x over previous
//
#include <hip/hip_runtime.h>
#include <hip/hip_bf16.h>

#define D 128
#define NH 256
#define K1 384
#define BM 64
#define E_TOTAL 320000
#define NNODES 10000

typedef __attribute__((ext_vector_type(8))) short bf16x8;
typedef __attribute__((ext_vector_type(4))) float f32x4;

__device__ __forceinline__ unsigned short f2b(float f) {
  unsigned int u = __builtin_bit_cast(unsigned int, f);
  u += 0x7fffu + ((u >> 16) & 1u);   // round-to-nearest-even
  return (unsigned short)(u >> 16);
}

// nodes fp32 -> bf16 table
__global__ void cast_nodes_kernel(const float* __restrict__ nodes,
                                  ushort* __restrict__ out) {
  int i = (blockIdx.x * 256 + threadIdx.x) * 4;
  float4 v = *(const float4*)(nodes + i);
  ushort4 b;
  b.x = f2b(v.x); b.y = f2b(v.y); b.z = f2b(v.z); b.w = f2b(v.w);
  *(ushort4*)(out + i) = b;
}

// Pack W1 (fp32 [512][256], rows 0..383 used) into MFMA-fragment order:
// chunk c = nt*12 + ks ; lane l holds W1[ks*32+(l>>4)*8 + j][nt*16+(l&15)]
__global__ void pack_w1_kernel(const float* __restrict__ W1,
                               ushort* __restrict__ W1p) {
  int c = blockIdx.x * 256 + threadIdx.x;   // 12288 threads
  int nt = c / (12 * 64);
  int rem = c % (12 * 64);
  int ks = rem >> 6;
  int l = rem & 63;
  int col = nt * 16 + (l & 15);
  int k0 = ks * 32 + (l >> 4) * 8;
  ushort* dst = W1p + (size_t)c * 8;
  #pragma unroll
  for (int j = 0; j < 8; ++j)
    dst[j] = f2b(W1[(size_t)(k0 + j) * NH + col]);
}

// Pack W2 (fp32 [256][128]) same fragment order: chunk c = nt2*8 + ks
__global__ void pack_w2_kernel(const float* __restrict__ W2,
                               ushort* __restrict__ W2p) {
  int c = blockIdx.x * 256 + threadIdx.x;   // 4096 threads
  int nt2 = c / (8 * 64);
  int rem = c % (8 * 64);
  int ks = rem >> 6;
  int l = rem & 63;
  int col = nt2 * 16 + (l & 15);
  int k0 = ks * 32 + (l >> 4) * 8;
  ushort* dst = W2p + (size_t)c * 8;
  #pragma unroll
  for (int j = 0; j < 8; ++j)
    dst[j] = f2b(W2[(size_t)(k0 + j) * D + col]);
}

// cvec[n] = b1[n] + sum_k globals[k] * W1[384+k][n]
__global__ void cvec_kernel(const float* __restrict__ W1,
                            const float* __restrict__ b1,
                            const float* __restrict__ g,
                            float* __restrict__ cvec) {
  int n = threadIdx.x;  // 256
  float acc = b1[n];
  for (int k = 0; k < D; ++k)
    acc += g[k] * W1[(size_t)(K1 + k) * NH + n];
  cvec[n] = acc;
}

// Swapped orientation (r8, verified) + Hs aliased onto Xs (48 KB LDS) +
// register diet -> 3 blocks/CU at __launch_bounds__(512,6).
__global__ __launch_bounds__(512, 6) void fused_kernel(
    const float* __restrict__ edges,
    const ushort* __restrict__ nodes_b,
    const int* __restrict__ receivers,
    const int* __restrict__ senders,
    const ushort* __restrict__ W1p,    // packed fragments, 16nt x 12ks x 64lane x 8
    const float* __restrict__ cvec,    // [256]
    const ushort* __restrict__ W2p,    // packed fragments, 8nt x 8ks x 64lane x 8
    const float* __restrict__ b2,      // [128]
    float* __restrict__ out) {
  // Xs: 64 x 384 bf16 (48 KB), byte ^= (row&7)<<4 swizzle.
  // Hs (64 x 256 bf16, 32 KB) ALIASES Xs: GEMM1 fully reads Xs before
  // epilogue-1 writes (guarded by an extra barrier).
  __shared__ char Xs[BM * 768];
  char* Hs = Xs;

  const int ebase = blockIdx.x * BM;
  const int tid = threadIdx.x;

  // ---- gather indices first
  const int gr0 = tid >> 4;
  const int gr1 = gr0 + 32;
  const int gc = (tid & 15) << 3;
  int idx_r0 = receivers[ebase + gr0];
  int idx_r1 = receivers[ebase + gr1];
  int idx_s0 = senders[ebase + gr0];
  int idx_s1 = senders[ebase + gr1];

  // ---- edge loads
  float4 ev[4];
  int er[4], ec[4];
  #pragma unroll
  for (int it = 0; it < 4; ++it) {
    int ch = tid + it * 512;
    er[it] = ch >> 5;
    ec[it] = (ch & 31) << 2;
    ev[it] = *(const float4*)(edges + (size_t)(ebase + er[it]) * D + ec[it]);
  }

  // ---- gathers
  uint4 gv[4];
  gv[0] = *(const uint4*)(nodes_b + (size_t)idx_r0 * D + gc);
  gv[1] = *(const uint4*)(nodes_b + (size_t)idx_r1 * D + gc);
  gv[2] = *(const uint4*)(nodes_b + (size_t)idx_s0 * D + gc);
  gv[3] = *(const uint4*)(nodes_b + (size_t)idx_s1 * D + gc);

  // ---- convert + LDS writes
  #pragma unroll
  for (int it = 0; it < 4; ++it) {
    ushort4 b;
    b.x = f2b(ev[it].x); b.y = f2b(ev[it].y); b.z = f2b(ev[it].z); b.w = f2b(ev[it].w);
    *(ushort4*)(Xs + er[it] * 768 + ((ec[it] * 2) ^ ((er[it] & 7) << 4))) = b;
  }
  {
    int cR = (D + gc) * 2, cS = (2 * D + gc) * 2;
    *(uint4*)(Xs + gr0 * 768 + (cR ^ ((gr0 & 7) << 4))) = gv[0];
    *(uint4*)(Xs + gr1 * 768 + (cR ^ ((gr1 & 7) << 4))) = gv[1];
    *(uint4*)(Xs + gr0 * 768 + (cS ^ ((gr0 & 7) << 4))) = gv[2];
    *(uint4*)(Xs + gr1 * 768 + (cS ^ ((gr1 & 7) << 4))) = gv[3];
  }
  __syncthreads();

  const int lane = tid & 63;
  const int wave = tid >> 6;     // GEMM1: wave owns hidden cols [32w, 32w+32)
  const int lr = lane & 15;
  const int kg = lane >> 4;
  const int wm3 = wave >> 1;     // GEMM2: out cols [32*wm3, 32*wm3+32)
  const int wn3 = wave & 1;      //        edges    [32*wn3, 32*wn3+32)

  // ---- GEMM1 (swapped): H^T[32h x 64e] += W1^T-frag (A) * X-row-frag (B)
  const ushort* w1base = W1p + (size_t)(wave * 2) * 12 * 512 + lane * 8;

  f32x4 acc[2][4] = {};   // [ht][et]
  bf16x8 aw[2][2];
  #pragma unroll
  for (int ht = 0; ht < 2; ++ht)
    aw[0][ht] = *(const bf16x8*)(w1base + (size_t)ht * 12 * 512);

  #pragma unroll
  for (int ks = 0; ks < 12; ++ks) {
    const int cur = ks & 1, nxt = cur ^ 1;
    if (ks < 11) {
      #pragma unroll
      for (int ht = 0; ht < 2; ++ht)
        aw[nxt][ht] = *(const bf16x8*)(w1base + (size_t)ht * 12 * 512 + (ks + 1) * 512);
    }
    const int k0 = ks * 32 + kg * 8;
    bf16x8 xb[4];
    #pragma unroll
    for (int et = 0; et < 4; ++et) {
      int row = et * 16 + lr;
      xb[et] = *(const bf16x8*)(Xs + row * 768 + ((k0 * 2) ^ ((row & 7) << 4)));
    }
    #pragma unroll
    for (int ht = 0; ht < 2; ++ht)
      #pragma unroll
      for (int et = 0; et < 4; ++et)
        acc[ht][et] = __builtin_amdgcn_mfma_f32_16x16x32_bf16(aw[cur][ht], xb[et], acc[ht][et], 0, 0, 0);
  }

  // prefetch first W2^T fragments + cvec quads (live across barrier only)
  const ushort* w2base = W2p + (size_t)(wm3 * 2) * 8 * 512 + lane * 8;
  bf16x8 aw2[2][2];
  #pragma unroll
  for (int mt = 0; mt < 2; ++mt)
    aw2[0][mt] = *(const bf16x8*)(w2base + (size_t)mt * 8 * 512);
  float4 cva = *(const float4*)(cvec + wave * 32 + kg * 4);
  float4 cvb = *(const float4*)(cvec + wave * 32 + 16 + kg * 4);

  // all waves must be DONE READING Xs before epilogue-1 overwrites it
  __syncthreads();

  // ---- epilogue 1: + cvec, relu -> bf16, vector ds_write_b64 (Hs aliases Xs)
  #pragma unroll
  for (int ht = 0; ht < 2; ++ht) {
    const float4 cvq = ht ? cvb : cva;
    const int h0b = (wave * 32 + ht * 16 + kg * 4) * 2;
    #pragma unroll
    for (int et = 0; et < 4; ++et) {
      int e = et * 16 + lr;
      float v0 = acc[ht][et][0] + cvq.x;
      float v1 = acc[ht][et][1] + cvq.y;
      float v2 = acc[ht][et][2] + cvq.z;
      float v3 = acc[ht][et][3] + cvq.w;
      v0 = v0 > 0.f ? v0 : 0.f;
      v1 = v1 > 0.f ? v1 : 0.f;
      v2 = v2 > 0.f ? v2 : 0.f;
      v3 = v3 > 0.f ? v3 : 0.f;
      uint2 pk;
      pk.x = (unsigned)f2b(v0) | ((unsigned)f2b(v1) << 16);
      pk.y = (unsigned)f2b(v2) | ((unsigned)f2b(v3) << 16);
      *(uint2*)(Hs + e * 512 + (h0b ^ ((e & 7) << 4))) = pk;
    }
  }
  __syncthreads();

  // ---- GEMM2 (swapped): out^T[32c x 32e] += W2^T-frag (A) * H-row-frag (B)
  float4 ba = *(const float4*)(b2 + wm3 * 32 + kg * 4);
  float4 bb2 = *(const float4*)(b2 + wm3 * 32 + 16 + kg * 4);
  f32x4 acc2[2][2] = {};  // [mt][et2]
  #pragma unroll
  for (int ks = 0; ks < 8; ++ks) {
    const int cur = ks & 1, nxt = cur ^ 1;
    if (ks < 7) {
      #pragma unroll
      for (int mt = 0; mt < 2; ++mt)
        aw2[nxt][mt] = *(const bf16x8*)(w2base + (size_t)mt * 8 * 512 + (ks + 1) * 512);
    }
    const int k0 = ks * 32 + kg * 8;
    bf16x8 hb[2];
    #pragma unroll
    for (int et2 = 0; et2 < 2; ++et2) {
      int e = wn3 * 32 + et2 * 16 + lr;
      hb[et2] = *(const bf16x8*)(Hs + e * 512 + ((k0 * 2) ^ ((e & 7) << 4)));
    }
    #pragma unroll
    for (int mt = 0; mt < 2; ++mt)
      #pragma unroll
      for (int et2 = 0; et2 < 2; ++et2)
        acc2[mt][et2] = __builtin_amdgcn_mfma_f32_16x16x32_bf16(aw2[cur][mt], hb[et2], acc2[mt][et2], 0, 0, 0);
  }

  // ---- epilogue 2: + b2, float4 stores (4 consecutive out cols of one edge)
  #pragma unroll
  for (int mt = 0; mt < 2; ++mt) {
    const float4 bq = mt ? bb2 : ba;
    const int c0 = wm3 * 32 + mt * 16 + kg * 4;
    #pragma unroll
    for (int et2 = 0; et2 < 2; ++et2) {
      int e = wn3 * 32 + et2 * 16 + lr;
      float4 o;
      o.x = acc2[mt][et2][0] + bq.x;
      o.y = acc2[mt][et2][1] + bq.y;
      o.z = acc2[mt][et2][2] + bq.z;
      o.w = acc2[mt][et2][3] + bq.w;
      *(float4*)(out + (size_t)(ebase + e) * D + c0) = o;
    }
  }
}

extern "C" void kernel_launch(void* const* d_in, const int* in_sizes, int n_in,
                              void* d_out, int out_size, void* d_ws, size_t ws_size,
                              hipStream_t stream) {
  const float* edges     = (const float*)d_in[0];
  const float* nodes     = (const float*)d_in[1];
  const float* globals_  = (const float*)d_in[2];
  const int*   receivers = (const int*)d_in[3];
  const int*   senders   = (const int*)d_in[4];
  const float* W1        = (const float*)d_in[5];
  const float* b1        = (const float*)d_in[6];
  const float* W2        = (const float*)d_in[7];
  const float* b2        = (const float*)d_in[8];
  float* out = (float*)d_out;

  char* ws = (char*)d_ws;
  ushort* nodes_b = (ushort*)ws;                                // 2,560,000 B
  ushort* W1p     = (ushort*)(ws + 2560000);                    //   196,608 B
  ushort* W2p     = (ushort*)(ws + 2560000 + 196608);           //    65,536 B
  float*  cvec    = (float*)(ws + 2560000 + 196608 + 65536);    //     1,024 B

  hipLaunchKernelGGL(cast_nodes_kernel, dim3(NNODES * D / 1024), dim3(256), 0, stream,
                     nodes, nodes_b);
  hipLaunchKernelGGL(pack_w1_kernel, dim3(48), dim3(256), 0, stream, W1, W1p);
  hipLaunchKernelGGL(pack_w2_kernel, dim3(16), dim3(256), 0, stream, W2, W2p);
  hipLaunchKernelGGL(cvec_kernel, dim3(1), dim3(256), 0, stream,
                     W1, b1, globals_, cvec);
  hipLaunchKernelGGL(fused_kernel, dim3(E_TOTAL / BM), dim3(512), 0, stream,
                     edges, nodes_b, receivers, senders, W1p, cvec, W2p, b2, out);
}

// Round 10
// 141.395 us; speedup vs baseline: 1.8633x; 1.0738x over previous
//
#include <hip/hip_runtime.h>
#include <hip/hip_bf16.h>

#define D 128
#define NH 256
#define K1 384
#define BM 64
#define E_TOTAL 320000
#define NNODES 10000

typedef __attribute__((ext_vector_type(8))) short bf16x8;
typedef __attribute__((ext_vector_type(4))) float f32x4;

__device__ __forceinline__ unsigned short f2b(float f) {
  unsigned int u = __builtin_bit_cast(unsigned int, f);
  u += 0x7fffu + ((u >> 16) & 1u);   // round-to-nearest-even
  return (unsigned short)(u >> 16);
}

// nodes fp32 -> bf16 table
__global__ void cast_nodes_kernel(const float* __restrict__ nodes,
                                  ushort* __restrict__ out) {
  int i = (blockIdx.x * 256 + threadIdx.x) * 4;
  float4 v = *(const float4*)(nodes + i);
  ushort4 b;
  b.x = f2b(v.x); b.y = f2b(v.y); b.z = f2b(v.z); b.w = f2b(v.w);
  *(ushort4*)(out + i) = b;
}

// Pack W1 (fp32 [512][256], rows 0..383 used) into MFMA-fragment order:
// chunk c = nt*12 + ks ; lane l holds W1[ks*32+(l>>4)*8 + j][nt*16+(l&15)]
__global__ void pack_w1_kernel(const float* __restrict__ W1,
                               ushort* __restrict__ W1p) {
  int c = blockIdx.x * 256 + threadIdx.x;   // 12288 threads
  int nt = c / (12 * 64);
  int rem = c % (12 * 64);
  int ks = rem >> 6;
  int l = rem & 63;
  int col = nt * 16 + (l & 15);
  int k0 = ks * 32 + (l >> 4) * 8;
  ushort* dst = W1p + (size_t)c * 8;
  #pragma unroll
  for (int j = 0; j < 8; ++j)
    dst[j] = f2b(W1[(size_t)(k0 + j) * NH + col]);
}

// Pack W2 (fp32 [256][128]) same fragment order: chunk c = nt2*8 + ks
__global__ void pack_w2_kernel(const float* __restrict__ W2,
                               ushort* __restrict__ W2p) {
  int c = blockIdx.x * 256 + threadIdx.x;   // 4096 threads
  int nt2 = c / (8 * 64);
  int rem = c % (8 * 64);
  int ks = rem >> 6;
  int l = rem & 63;
  int col = nt2 * 16 + (l & 15);
  int k0 = ks * 32 + (l >> 4) * 8;
  ushort* dst = W2p + (size_t)c * 8;
  #pragma unroll
  for (int j = 0; j < 8; ++j)
    dst[j] = f2b(W2[(size_t)(k0 + j) * D + col]);
}

// cvec[n] = b1[n] + sum_k globals[k] * W1[384+k][n]
__global__ void cvec_kernel(const float* __restrict__ W1,
                            const float* __restrict__ b1,
                            const float* __restrict__ g,
                            float* __restrict__ cvec) {
  int n = threadIdx.x;  // 256
  float acc = b1[n];
  for (int k = 0; k < D; ++k)
    acc += g[k] * W1[(size_t)(K1 + k) * NH + n];
  cvec[n] = acc;
}

// r3 champion structure + depth-2-ahead weight prefetch (3 rotating buffers).
__global__ __launch_bounds__(512, 4) void fused_kernel(
    const float* __restrict__ edges,
    const ushort* __restrict__ nodes_b,
    const int* __restrict__ receivers,
    const int* __restrict__ senders,
    const ushort* __restrict__ W1p,    // packed fragments, 16nt x 12ks x 64lane x 8
    const float* __restrict__ cvec,    // [256]
    const ushort* __restrict__ W2p,    // packed fragments, 8nt x 8ks x 64lane x 8
    const float* __restrict__ b2,      // [128]
    float* __restrict__ out) {
  __shared__ char Xs[BM * 768];   // 64 x 384 bf16, byte ^= (row&7)<<4 swizzle
  __shared__ char Hs[BM * 512];   // 64 x 256 bf16, same swizzle

  const int ebase = blockIdx.x * BM;
  const int tid = threadIdx.x;

  // ---- gather indices first
  const int gr0 = tid >> 4;
  const int gr1 = gr0 + 32;
  const int gc = (tid & 15) << 3;
  int idx_r0 = receivers[ebase + gr0];
  int idx_r1 = receivers[ebase + gr1];
  int idx_s0 = senders[ebase + gr0];
  int idx_s1 = senders[ebase + gr1];

  // ---- edge loads
  float4 ev[4];
  int er[4], ec[4];
  #pragma unroll
  for (int it = 0; it < 4; ++it) {
    int ch = tid + it * 512;
    er[it] = ch >> 5;
    ec[it] = (ch & 31) << 2;
    ev[it] = *(const float4*)(edges + (size_t)(ebase + er[it]) * D + ec[it]);
  }

  // ---- gathers
  uint4 gv[4];
  gv[0] = *(const uint4*)(nodes_b + (size_t)idx_r0 * D + gc);
  gv[1] = *(const uint4*)(nodes_b + (size_t)idx_r1 * D + gc);
  gv[2] = *(const uint4*)(nodes_b + (size_t)idx_s0 * D + gc);
  gv[3] = *(const uint4*)(nodes_b + (size_t)idx_s1 * D + gc);

  // ---- convert + LDS writes
  #pragma unroll
  for (int it = 0; it < 4; ++it) {
    ushort4 b;
    b.x = f2b(ev[it].x); b.y = f2b(ev[it].y); b.z = f2b(ev[it].z); b.w = f2b(ev[it].w);
    *(ushort4*)(Xs + er[it] * 768 + ((ec[it] * 2) ^ ((er[it] & 7) << 4))) = b;
  }
  {
    int cR = (D + gc) * 2, cS = (2 * D + gc) * 2;
    *(uint4*)(Xs + gr0 * 768 + (cR ^ ((gr0 & 7) << 4))) = gv[0];
    *(uint4*)(Xs + gr1 * 768 + (cR ^ ((gr1 & 7) << 4))) = gv[1];
    *(uint4*)(Xs + gr0 * 768 + (cS ^ ((gr0 & 7) << 4))) = gv[2];
    *(uint4*)(Xs + gr1 * 768 + (cS ^ ((gr1 & 7) << 4))) = gv[3];
  }
  __syncthreads();

  const int lane = tid & 63;
  const int wave = tid >> 6;     // GEMM1: wave owns cols [32w,32w+32), all 64 rows
  const int lr = lane & 15;
  const int kg = lane >> 4;

  // epilogue constants (latency hidden under GEMM1)
  float cv[2];
  #pragma unroll
  for (int n = 0; n < 2; ++n) cv[n] = cvec[wave * 32 + n * 16 + lr];
  const int wm2 = wave >> 2;     // GEMM2: 2x4 wave grid, 32x32 out tile each
  const int wn2 = wave & 3;
  float bias2[2];
  #pragma unroll
  for (int n = 0; n < 2; ++n) bias2[n] = b2[wn2 * 32 + n * 16 + lr];

  // ---- GEMM1: [64x384] @ [384x32-per-wave], packed-fragment B (1KB/instr),
  // depth-2-ahead prefetch: 3 rotating buffers, issue ks+2 at iter ks.
  const ushort* w1base = W1p + (size_t)(wave * 2) * 12 * 512 + lane * 8;

  f32x4 acc[4][2] = {};
  bf16x8 bb[3][2];
  #pragma unroll
  for (int p = 0; p < 2; ++p)
    #pragma unroll
    for (int n = 0; n < 2; ++n)
      bb[p][n] = *(const bf16x8*)(w1base + (size_t)n * 12 * 512 + p * 512);

  #pragma unroll
  for (int ks = 0; ks < 12; ++ks) {
    const int cur = ks % 3;
    if (ks < 10) {
      const int ld = (ks + 2) % 3;
      #pragma unroll
      for (int n = 0; n < 2; ++n)
        bb[ld][n] = *(const bf16x8*)(w1base + (size_t)n * 12 * 512 + (ks + 2) * 512);
    }
    const int k0 = ks * 32 + kg * 8;
    bf16x8 a[4];
    #pragma unroll
    for (int m = 0; m < 4; ++m) {
      int row = m * 16 + lr;
      a[m] = *(const bf16x8*)(Xs + row * 768 + ((k0 * 2) ^ ((row & 7) << 4)));
    }
    __builtin_amdgcn_s_setprio(1);
    #pragma unroll
    for (int m = 0; m < 4; ++m)
      #pragma unroll
      for (int n = 0; n < 2; ++n)
        acc[m][n] = __builtin_amdgcn_mfma_f32_16x16x32_bf16(a[m], bb[cur][n], acc[m][n], 0, 0, 0);
    __builtin_amdgcn_s_setprio(0);
  }

  // prefetch first two W2 fragment sets (no Hs dependency) before the barrier
  const ushort* w2base = W2p + (size_t)(wn2 * 2) * 8 * 512 + lane * 8;
  bf16x8 b2b[3][2];
  #pragma unroll
  for (int p = 0; p < 2; ++p)
    #pragma unroll
    for (int n = 0; n < 2; ++n)
      b2b[p][n] = *(const bf16x8*)(w2base + (size_t)n * 8 * 512 + p * 512);

  // ---- epilogue 1: + cvec, relu, -> bf16 Hs
  #pragma unroll
  for (int n = 0; n < 2; ++n) {
    int col = wave * 32 + n * 16 + lr;
    #pragma unroll
    for (int m = 0; m < 4; ++m) {
      #pragma unroll
      for (int r = 0; r < 4; ++r) {
        int row = m * 16 + kg * 4 + r;
        float v = acc[m][n][r] + cv[n];
        v = v > 0.f ? v : 0.f;
        *(ushort*)(Hs + row * 512 + ((col * 2) ^ ((row & 7) << 4))) = f2b(v);
      }
    }
  }
  __syncthreads();

  // ---- GEMM2: [64x256] @ [256x128], 2x4 wave grid, depth-2-ahead prefetch
  f32x4 acc2[2][2] = {};
  #pragma unroll
  for (int ks = 0; ks < 8; ++ks) {
    const int cur = ks % 3;
    if (ks < 6) {
      const int ld = (ks + 2) % 3;
      #pragma unroll
      for (int n = 0; n < 2; ++n)
        b2b[ld][n] = *(const bf16x8*)(w2base + (size_t)n * 8 * 512 + (ks + 2) * 512);
    }
    const int k0 = ks * 32 + kg * 8;
    bf16x8 a[2];
    #pragma unroll
    for (int m = 0; m < 2; ++m) {
      int row = wm2 * 32 + m * 16 + lr;
      a[m] = *(const bf16x8*)(Hs + row * 512 + ((k0 * 2) ^ ((row & 7) << 4)));
    }
    __builtin_amdgcn_s_setprio(1);
    #pragma unroll
    for (int m = 0; m < 2; ++m)
      #pragma unroll
      for (int n = 0; n < 2; ++n)
        acc2[m][n] = __builtin_amdgcn_mfma_f32_16x16x32_bf16(a[m], b2b[cur][n], acc2[m][n], 0, 0, 0);
    __builtin_amdgcn_s_setprio(0);
  }

  // ---- epilogue 2: + b2, store fp32 (wave's 32x32 tile)
  #pragma unroll
  for (int n = 0; n < 2; ++n) {
    int col = wn2 * 32 + n * 16 + lr;
    #pragma unroll
    for (int m = 0; m < 2; ++m) {
      #pragma unroll
      for (int r = 0; r < 4; ++r) {
        int row = wm2 * 32 + m * 16 + kg * 4 + r;
        out[(size_t)(ebase + row) * D + col] = acc2[m][n][r] + bias2[n];
      }
    }
  }
}

extern "C" void kernel_launch(void* const* d_in, const int* in_sizes, int n_in,
                              void* d_out, int out_size, void* d_ws, size_t ws_size,
                              hipStream_t stream) {
  const float* edges     = (const float*)d_in[0];
  const float* nodes     = (const float*)d_in[1];
  const float* globals_  = (const float*)d_in[2];
  const int*   receivers = (const int*)d_in[3];
  const int*   senders   = (const int*)d_in[4];
  const float* W1        = (const float*)d_in[5];
  const float* b1        = (const float*)d_in[6];
  const float* W2        = (const float*)d_in[7];
  const float* b2        = (const float*)d_in[8];
  float* out = (float*)d_out;

  char* ws = (char*)d_ws;
  ushort* nodes_b = (ushort*)ws;                                // 2,560,000 B
  ushort* W1p     = (ushort*)(ws + 2560000);                    //   196,608 B
  ushort* W2p     = (ushort*)(ws + 2560000 + 196608);           //    65,536 B
  float*  cvec    = (float*)(ws + 2560000 + 196608 + 65536);    //     1,024 B

  hipLaunchKernelGGL(cast_nodes_kernel, dim3(NNODES * D / 1024), dim3(256), 0, stream,
                     nodes, nodes_b);
  hipLaunchKernelGGL(pack_w1_kernel, dim3(48), dim3(256), 0, stream, W1, W1p);
  hipLaunchKernelGGL(pack_w2_kernel, dim3(16), dim3(256), 0, stream, W2, W2p);
  hipLaunchKernelGGL(cvec_kernel, dim3(1), dim3(256), 0, stream,
                     W1, b1, globals_, cvec);
  hipLaunchKernelGGL(fused_kernel, dim3(E_TOTAL / BM), dim3(512), 0, stream,
                     edges, nodes_b, receivers, senders, W1p, cvec, W2p, b2, out);
}